// Round 9
// baseline (61579.395 us; speedup 1.0000x reference)
//
#include <hip/hip_runtime.h>
#include <math.h>

#define BSZ 2048
#define MM  256
#define EE  128
#define HSS 512
#define HPP 256
#define NOWN 64
#define NBLK 128
#define TPB 512
#define ROWS 4

typedef float f4 __attribute__((ext_vector_type(4)));

// flags: [0..63]=evFlag [64..127]=sliceFlag [128..191]=rowFlag [192..255]=scFlag [256..319]=bulkFlag
#define OFF_PE    512
#define OFF_R0    (OFF_PE + MM*EE)
#define OFF_W0    (OFF_R0 + BSZ)
#define OFF_MP    (OFF_W0 + BSZ*MM)          // [2][MM][EE]
#define OFF_SW    (OFF_MP + 2*MM*EE)         // [2][MM][MM]
#define OFF_EV    (OFF_SW + 2*MM*MM)         // [2][NOWN][EE]
#define OFF_ES    (OFF_EV + 2*NOWN*EE)       // [2][NOWN]
#define OFF_CS    (OFF_ES + 2*NOWN)          // Wemb@Ws[0:128]: 4*HSS
#define OFF_CBS   (OFF_CS + 4*HSS)
#define OFF_CP    (OFF_CBS + HSS)            // Wemb@Wp1[0:128]: 4*HPP
#define OFF_CBP   (OFF_CP + 4*HPP)
#define OFF_CR    (OFF_CBP + HPP)            // Wemb@Wr1: 4*HSS
#define OFF_CBR   (OFF_CR + 4*HSS)
#define OFF_CSR   (OFF_CBR + HSS)
#define OFF_CW2   (OFF_CSR + HSS)            // Wemb@Ww1: 4*HSS
#define OFF_CBW   (OFF_CW2 + 4*HSS)
#define OFF_CSW   (OFF_CBW + HSS)
#define OFF_BD    (OFF_CSW + HSS)            // NOWN*ROWS
#define OFF_BP    (OFF_BD + NOWN*ROWS)       // NOWN*ROWS*EE
#define OFF_PWRD  (OFF_BP + NOWN*ROWS*EE)    // NOWN*ROWS*HSS (P@Wr1, helper->owner)
#define OFF_PWRpe (OFF_PWRD + NOWN*ROWS*HSS) // MM*HSS (pe@Wr1)
#define OFF_PWWpe (OFF_PWRpe + MM*HSS)       // MM*HSS (pe@Ww1)
#define OFF_MSR   (OFF_PWWpe + MM*HSS)       // [2][HSS]
#define OFF_MSW   (OFF_MSR + 2*HSS)          // [2][HSS]
#define OFF_SCAL  (OFF_MSW + 2*HSS)          // MM*4

struct KParams {
  const float *state, *mem0, *Wemb, *bemb, *Wr1, *br1, *Wr2, *br2;
  const float *Ww1, *bw1, *Ww2, *bw2, *Ws, *bs, *Wa, *ba, *Wc, *bc;
  const float *Wp1, *bp1, *Wp2, *bp2;
  float *out;
  float *ws;
};

__device__ __forceinline__ float ldA(const float* p) {
  return __hip_atomic_load(p, __ATOMIC_RELAXED, __HIP_MEMORY_SCOPE_AGENT);
}
__device__ __forceinline__ void stA(float* p, float v) {
  __hip_atomic_store(p, v, __ATOMIC_RELAXED, __HIP_MEMORY_SCOPE_AGENT);
}
__device__ __forceinline__ unsigned ldAu(const unsigned* p) {
  return __hip_atomic_load(p, __ATOMIC_RELAXED, __HIP_MEMORY_SCOPE_AGENT);
}
__device__ __forceinline__ void stAu(unsigned* p, unsigned v) {
  __hip_atomic_store(p, v, __ATOMIC_RELAXED, __HIP_MEMORY_SCOPE_AGENT);
}

__device__ __forceinline__ void ldA4x8(const float* p, int strideF, f4* v) {
  const float *p1=p+strideF, *p2=p+2*strideF, *p3=p+3*strideF,
              *p4=p+4*strideF, *p5=p+5*strideF, *p6=p+6*strideF, *p7=p+7*strideF;
  asm volatile(
    "global_load_dwordx4 %0, %8, off sc0 sc1\n\t"
    "global_load_dwordx4 %1, %9, off sc0 sc1\n\t"
    "global_load_dwordx4 %2, %10, off sc0 sc1\n\t"
    "global_load_dwordx4 %3, %11, off sc0 sc1\n\t"
    "global_load_dwordx4 %4, %12, off sc0 sc1\n\t"
    "global_load_dwordx4 %5, %13, off sc0 sc1\n\t"
    "global_load_dwordx4 %6, %14, off sc0 sc1\n\t"
    "global_load_dwordx4 %7, %15, off sc0 sc1\n\t"
    "s_waitcnt vmcnt(0)"
    : "=&v"(v[0]), "=&v"(v[1]), "=&v"(v[2]), "=&v"(v[3]),
      "=&v"(v[4]), "=&v"(v[5]), "=&v"(v[6]), "=&v"(v[7])
    : "v"(p), "v"(p1), "v"(p2), "v"(p3), "v"(p4), "v"(p5), "v"(p6), "v"(p7)
    : "memory");
}
__device__ __forceinline__ void ldA4x4(const float* p, int strideF, f4* v) {
  const float *p1=p+strideF, *p2=p+2*strideF, *p3=p+3*strideF;
  asm volatile(
    "global_load_dwordx4 %0, %4, off sc0 sc1\n\t"
    "global_load_dwordx4 %1, %5, off sc0 sc1\n\t"
    "global_load_dwordx4 %2, %6, off sc0 sc1\n\t"
    "global_load_dwordx4 %3, %7, off sc0 sc1\n\t"
    "s_waitcnt vmcnt(0)"
    : "=&v"(v[0]), "=&v"(v[1]), "=&v"(v[2]), "=&v"(v[3])
    : "v"(p), "v"(p1), "v"(p2), "v"(p3)
    : "memory");
}
__device__ __forceinline__ f4 ldA4(const float* p) {
  f4 r;
  asm volatile("global_load_dwordx4 %0, %1, off sc0 sc1\n\ts_waitcnt vmcnt(0)"
    : "=&v"(r) : "v"(p) : "memory");
  return r;
}

__device__ __forceinline__ void drainSync() {
  asm volatile("s_waitcnt vmcnt(0)" ::: "memory");
  __syncthreads();
}

__device__ __forceinline__ float brs(float v, float* s8, int tid) {
  for (int o = 32; o > 0; o >>= 1) v += __shfl_down(v, o, 64);
  __syncthreads();
  if ((tid & 63) == 0) s8[tid >> 6] = v;
  __syncthreads();
  float r = s8[0]+s8[1]+s8[2]+s8[3]+s8[4]+s8[5]+s8[6]+s8[7];
  __syncthreads();
  return r;
}

template<int N>
__device__ __forceinline__ void brsN(float* v, float* sred, int tid) {
  #pragma unroll
  for (int k = 0; k < N; ++k)
    for (int o = 32; o > 0; o >>= 1) v[k] += __shfl_down(v[k], o, 64);
  __syncthreads();
  if ((tid & 63) == 0) {
    const int w = tid >> 6;
    #pragma unroll
    for (int k = 0; k < N; ++k) sred[k*8 + w] = v[k];
  }
  __syncthreads();
  #pragma unroll
  for (int k = 0; k < N; ++k) {
    float s = sred[k*8 + 0];
    #pragma unroll
    for (int w = 1; w < 8; ++w) s += sred[k*8 + w];
    v[k] = s;
  }
  __syncthreads();
}

__global__ __launch_bounds__(TPB)
void toyac_kernel(KParams p) {
  const int g = blockIdx.x;
  const int tid = threadIdx.x;
  float* ws = p.ws;
  unsigned* bar = (unsigned*)p.ws;
  const int isOwner = (g < NOWN);
  const int og = isOwner ? g : (g - NOWN);
  const int c0 = ROWS * og;

  __shared__ float sBuf[8192];
  __shared__ float sPW[ROWS][HSS];
  __shared__ float sH4[ROWS][HSS];     // helper hC; alias sEv in dBulk
  __shared__ float sX[ROWS][EE];
  __shared__ float sP[ROWS][EE];
  __shared__ float sPE[ROWS][EE];
  __shared__ float sMSR[HSS];          // owner MSR; also P0b hv
  __shared__ float sMSWv[HSS];
  __shared__ float sMS[EE];
  __shared__ float sMS2[EE];
  __shared__ float sSE[EE];
  __shared__ float sP1[HPP];
  __shared__ float sD[ROWS];
  __shared__ float sR48[48];
  __shared__ float s8[8];
  __shared__ float sRed[16];
  __shared__ float sSm[40];

  float (*sEv)[MM] = (float(*)[MM])sH4;
  float* sHv = sMSR;

  const int hq = (tid & 127) * 4;
  const int eg4 = tid >> 7;

  // P@W stream: [4][EE] LDS src x W[128][512] -> sPW[4][512]
  auto streamPW = [&](const float* W, float (*src)[EE]) {
    {
      f4 a0={0.f,0.f,0.f,0.f},a1=a0,a2=a0,a3=a0;
      const float* base = W + (size_t)(eg4*32)*HSS + hq;
      for (int i = 0; i < 32; ++i) {
        f4 w = *(const f4*)(base + (size_t)i*HSS);
        int e = eg4*32 + i;
        a0 += src[0][e]*w; a1 += src[1][e]*w; a2 += src[2][e]*w; a3 += src[3][e]*w;
      }
      *(f4*)(sBuf + ((size_t)eg4*ROWS + 0)*HSS + hq) = a0;
      *(f4*)(sBuf + ((size_t)eg4*ROWS + 1)*HSS + hq) = a1;
      *(f4*)(sBuf + ((size_t)eg4*ROWS + 2)*HSS + hq) = a2;
      *(f4*)(sBuf + ((size_t)eg4*ROWS + 3)*HSS + hq) = a3;
    }
    __syncthreads();
    #pragma unroll
    for (int r = 0; r < ROWS; ++r)
      sPW[r][tid] = sBuf[(0*ROWS+r)*HSS+tid] + sBuf[(1*ROWS+r)*HSS+tid]
                  + sBuf[(2*ROWS+r)*HSS+tid] + sBuf[(3*ROWS+r)*HSS+tid];
    __syncthreads();
  };

  // ================= P0a =================
  if (isOwner) {
    const int e = tid & 127, r = tid >> 7, c = c0 + r;
    double dv = exp(-(double)(2*(e>>1)) * log(10000.0) / 128.0);
    double arg = (double)c * dv;
    float pev = ((e & 1) == 0) ? (float)sin(arg) : (float)cos(arg);
    stA(ws + OFF_PE + (size_t)c*EE + e, pev);
    sPE[r][e] = pev;
    float m0v = p.mem0[(size_t)c*EE + e] + pev;
    stA(ws + OFF_MP + (size_t)c*EE + e, m0v);
    sX[r][e] = m0v;
    if (g == 0) {
      int j = tid;
      { // CS/CBS from Ws[0:128]
        float a0=0.f,a1=0.f,a2=0.f,a3=0.f,cb=0.f;
        for (int ee = 0; ee < EE; ++ee) {
          float wv = p.Ws[(size_t)ee*HSS + j];
          a0 += p.Wemb[ee]*wv; a1 += p.Wemb[EE+ee]*wv;
          a2 += p.Wemb[2*EE+ee]*wv; a3 += p.Wemb[3*EE+ee]*wv;
          cb += p.bemb[ee]*wv;
        }
        stA(ws+OFF_CS+j, a0); stA(ws+OFF_CS+HSS+j, a1);
        stA(ws+OFF_CS+2*HSS+j, a2); stA(ws+OFF_CS+3*HSS+j, a3);
        stA(ws+OFF_CBS+j, cb);
      }
      { // CR/CBR/CSR from Wr1, CW2/CBW/CSW from Ww1
        float r0=0.f,r1=0.f,r2=0.f,r3=0.f,rb=0.f,rc=0.f;
        float w0=0.f,w1=0.f,w2=0.f,w3=0.f,wb=0.f,wc=0.f;
        for (int ee = 0; ee < EE; ++ee) {
          float wr = p.Wr1[(size_t)ee*HSS + j];
          float wwv = p.Ww1[(size_t)ee*HSS + j];
          float we0=p.Wemb[ee], we1=p.Wemb[EE+ee], we2=p.Wemb[2*EE+ee], we3=p.Wemb[3*EE+ee], wbe=p.bemb[ee];
          r0+=we0*wr; r1+=we1*wr; r2+=we2*wr; r3+=we3*wr; rb+=wbe*wr; rc+=wr;
          w0+=we0*wwv; w1+=we1*wwv; w2+=we2*wwv; w3+=we3*wwv; wb+=wbe*wwv; wc+=wwv;
        }
        stA(ws+OFF_CR+j, r0); stA(ws+OFF_CR+HSS+j, r1);
        stA(ws+OFF_CR+2*HSS+j, r2); stA(ws+OFF_CR+3*HSS+j, r3);
        stA(ws+OFF_CBR+j, rb); stA(ws+OFF_CSR+j, rc);
        stA(ws+OFF_CW2+j, w0); stA(ws+OFF_CW2+HSS+j, w1);
        stA(ws+OFF_CW2+2*HSS+j, w2); stA(ws+OFF_CW2+3*HSS+j, w3);
        stA(ws+OFF_CBW+j, wb); stA(ws+OFF_CSW+j, wc);
      }
      if (tid < HPP) { // CP/CBP from Wp1[0:128]
        int k = tid;
        float a0=0.f,a1=0.f,a2=0.f,a3=0.f,cb=0.f;
        for (int ee = 0; ee < EE; ++ee) {
          float wv = p.Wp1[(size_t)ee*HPP + k];
          a0 += p.Wemb[ee]*wv; a1 += p.Wemb[EE+ee]*wv;
          a2 += p.Wemb[2*EE+ee]*wv; a3 += p.Wemb[3*EE+ee]*wv;
          cb += p.bemb[ee]*wv;
        }
        stA(ws+OFF_CP+k, a0); stA(ws+OFF_CP+HPP+k, a1);
        stA(ws+OFF_CP+2*HPP+k, a2); stA(ws+OFF_CP+3*HPP+k, a3);
        stA(ws+OFF_CBP+k, cb);
      }
    }
  }

  // ================= P0b: per-step R0, W0 (striped over 128 blocks) =================
  for (int t = g; t < BSZ; t += NBLK) {
    __syncthreads();
    if (tid < EE) {
      const float* st = p.state + (size_t)t*4;
      sSE[tid] = st[0]*p.Wemb[tid] + st[1]*p.Wemb[EE+tid]
               + st[2]*p.Wemb[2*EE+tid] + st[3]*p.Wemb[3*EE+tid] + p.bemb[tid];
    }
    __syncthreads();
    { // reader score r0
      f4 a = {0.f,0.f,0.f,0.f};
      const float* base = p.Wr1 + (size_t)(eg4*32)*HSS + hq;
      for (int i = 0; i < 32; ++i)
        a += sSE[eg4*32 + i] * (*(const f4*)(base + (size_t)i*HSS));
      *(f4*)(sBuf + (size_t)eg4*HSS + hq) = a;
      __syncthreads();
      int h = tid;
      float hid = sBuf[h] + sBuf[HSS+h] + sBuf[2*HSS+h] + sBuf[3*HSS+h] + p.br1[h];
      float v = fmaxf(hid, 0.f) * p.Wr2[h];
      float sc = brs(v, s8, tid);
      if (tid == 0) stA(ws + OFF_R0 + t, sc + p.br2[0]);
      __syncthreads();
    }
    { // writer row0
      f4 a = {0.f,0.f,0.f,0.f};
      const float* base = p.Ww1 + (size_t)(eg4*32)*HSS + hq;
      for (int i = 0; i < 32; ++i)
        a += sSE[eg4*32 + i] * (*(const f4*)(base + (size_t)i*HSS));
      *(f4*)(sBuf + (size_t)eg4*HSS + hq) = a;
      __syncthreads();
      int h = tid;
      sHv[h] = fmaxf(sBuf[h] + sBuf[HSS+h] + sBuf[2*HSS+h] + sBuf[3*HSS+h] + p.bw1[h], 0.f);
      __syncthreads();
      const int cq = (tid & 63) * 4, hg = tid >> 6;
      f4 q = {0.f,0.f,0.f,0.f};
      const float* b2 = p.Ww2 + (size_t)(hg*64)*MM + cq;
      for (int i = 0; i < 64; ++i)
        q += sHv[hg*64 + i] * (*(const f4*)(b2 + (size_t)i*MM));
      *(f4*)(sBuf + (size_t)hg*MM + cq) = q;
      __syncthreads();
      if (tid < MM) {
        float s = 0.f;
        #pragma unroll
        for (int k = 0; k < 8; ++k) s += sBuf[(size_t)k*MM + tid];
        stA(ws + OFF_W0 + (size_t)t*MM + tid, s + p.bw2[tid]);
      }
      __syncthreads();
    }
  }

  auto ww2pass = [&](float* swdst) {
    const int cq = (tid & 63) * 4, hg = tid >> 6;
    f4 q0={0.f,0.f,0.f,0.f},q1=q0,q2=q0,q3=q0;
    const float* b2 = p.Ww2 + (size_t)(hg*64)*MM + cq;
    for (int i = 0; i < 64; ++i) {
      f4 w = *(const f4*)(b2 + (size_t)i*MM);
      int h = hg*64 + i;
      q0 += sH4[0][h]*w; q1 += sH4[1][h]*w; q2 += sH4[2][h]*w; q3 += sH4[3][h]*w;
    }
    *(f4*)(sBuf + ((size_t)hg*ROWS + 0)*MM + cq) = q0;
    *(f4*)(sBuf + ((size_t)hg*ROWS + 1)*MM + cq) = q1;
    *(f4*)(sBuf + ((size_t)hg*ROWS + 2)*MM + cq) = q2;
    *(f4*)(sBuf + ((size_t)hg*ROWS + 3)*MM + cq) = q3;
    __syncthreads();
    {
      const int col = tid & 255, rp = tid >> 8;
      #pragma unroll
      for (int rr = 0; rr < 2; ++rr) {
        int r = rp*2 + rr;
        float s = 0.f;
        #pragma unroll
        for (int k = 0; k < 8; ++k) s += sBuf[((size_t)k*ROWS + r)*MM + col];
        stA(swdst + (size_t)(c0 + r)*MM + col, s + p.bw2[col]);
      }
    }
  };

  auto dBulkH = [&](int tt) {
    float* swc = ws + OFF_SW + (size_t)(tt&1)*MM*MM;
    float* mpc = ws + OFF_MP + (size_t)(tt&1)*MM*EE;
    float ex[ROWS] = {0.f,0.f,0.f,0.f};
    if (tid < MM) {
      f4 s = ldA4(swc + (size_t)tid*MM + c0);
      #pragma unroll
      for (int r = 0; r < ROWS; ++r) { ex[r] = expf(s[r]); sEv[r][tid] = ex[r]; }
    }
    brsN<ROWS>(ex, sR48, tid);
    if (tid == 0) {
      stA(ws + OFF_BD + og*ROWS + 0, ex[0]);
      stA(ws + OFF_BD + og*ROWS + 1, ex[1]);
      stA(ws + OFF_BD + og*ROWS + 2, ex[2]);
      stA(ws + OFF_BD + og*ROWS + 3, ex[3]);
    }
    {
      const int e4 = (tid & 31) * 4, rg = tid >> 5;
      f4 a0={0.f,0.f,0.f,0.f},a1=a0,a2=a0,a3=a0;
      const float* base = mpc + (size_t)(rg*16)*EE + e4;
      f4 vv[8];
      ldA4x8(base, EE, vv);
      #pragma unroll
      for (int i = 0; i < 8; ++i) {
        int r0 = rg*16 + i;
        a0 += sEv[0][r0]*vv[i]; a1 += sEv[1][r0]*vv[i];
        a2 += sEv[2][r0]*vv[i]; a3 += sEv[3][r0]*vv[i];
      }
      ldA4x8(base + 8*EE, EE, vv);
      #pragma unroll
      for (int i = 0; i < 8; ++i) {
        int r0 = rg*16 + 8 + i;
        a0 += sEv[0][r0]*vv[i]; a1 += sEv[1][r0]*vv[i];
        a2 += sEv[2][r0]*vv[i]; a3 += sEv[3][r0]*vv[i];
      }
      *(f4*)(sBuf + ((size_t)0*16 + rg)*EE + e4) = a0;
      *(f4*)(sBuf + ((size_t)1*16 + rg)*EE + e4) = a1;
      *(f4*)(sBuf + ((size_t)2*16 + rg)*EE + e4) = a2;
      *(f4*)(sBuf + ((size_t)3*16 + rg)*EE + e4) = a3;
    }
    __syncthreads();
    {
      const int e = tid & 127, r = tid >> 7;
      float s = 0.f;
      #pragma unroll
      for (int q = 0; q < 16; ++q) s += sBuf[((size_t)r*16 + q)*EE + e];
      sP[r][e] = s;
      stA(ws + OFF_BP + ((size_t)og*ROWS + r)*EE + e, s);
    }
    __syncthreads();
  };

  // ================= main =================
  if (isOwner) {
    // -------- OWNER prologue --------
    const f4 wcol = *(const f4*)(p.Ww2 + (size_t)tid*MM + c0);
    const float rBr1 = p.br1[tid], rWr2 = p.Wr2[tid], rBw1v = p.bw1[tid];
    drainSync();
    if (tid == 0) stAu(&bar[128+g], 1u);   // rows(0)+pe ready
    streamPW(p.Wr1, sPE);
    float rPWRpe[ROWS];
    #pragma unroll
    for (int r = 0; r < ROWS; ++r) {
      ws[OFF_PWRpe + (size_t)(c0+r)*HSS + tid] = sPW[r][tid];
      rPWRpe[r] = sPW[r][tid];
    }
    __syncthreads();
    { // stageA_full(0) -> EV/ES parity0
      {
        f4 a0={0.f,0.f,0.f,0.f},a1=a0,a2=a0,a3=a0;
        const float* base = p.Wr1 + (size_t)(eg4*32)*HSS + hq;
        for (int i = 0; i < 32; ++i) {
          f4 w = *(const f4*)(base + (size_t)i*HSS);
          int e = eg4*32 + i;
          a0 += sX[0][e]*w; a1 += sX[1][e]*w; a2 += sX[2][e]*w; a3 += sX[3][e]*w;
        }
        *(f4*)(sBuf + ((size_t)eg4*ROWS + 0)*HSS + hq) = a0;
        *(f4*)(sBuf + ((size_t)eg4*ROWS + 1)*HSS + hq) = a1;
        *(f4*)(sBuf + ((size_t)eg4*ROWS + 2)*HSS + hq) = a2;
        *(f4*)(sBuf + ((size_t)eg4*ROWS + 3)*HSS + hq) = a3;
      }
      __syncthreads();
      float sc[ROWS];
      #pragma unroll
      for (int r = 0; r < ROWS; ++r) {
        float hid = sBuf[(0*ROWS+r)*HSS+tid] + sBuf[(1*ROWS+r)*HSS+tid]
                  + sBuf[(2*ROWS+r)*HSS+tid] + sBuf[(3*ROWS+r)*HSS+tid] + rBr1;
        sc[r] = fmaxf(hid, 0.f) * rWr2;
      }
      brsN<ROWS>(sc, sR48, tid);
      float es[ROWS];
      #pragma unroll
      for (int r = 0; r < ROWS; ++r) es[r] = expf(sc[r] + p.br2[0]);
      if (tid < EE) {
        float v = es[0]*sX[0][tid] + es[1]*sX[1][tid] + es[2]*sX[2][tid] + es[3]*sX[3][tid];
        stA(ws + OFF_EV + (size_t)g*EE + tid, v);
      }
      if (tid == 0) stA(ws + OFF_ES + g, es[0]+es[1]+es[2]+es[3]);
    }
    drainSync();
    if (tid == 0) stAu(&bar[g], 1u);       // EV(0) ready
    // wait all evFlag>=1 (owner0 composed done), preload composed regs
    if (tid < NOWN) { while (ldAu(&bar[tid]) < 1u) __builtin_amdgcn_s_sleep(1); }
    __syncthreads();
    const float rCS0=ldA(ws+OFF_CS+tid), rCS1=ldA(ws+OFF_CS+HSS+tid),
                rCS2=ldA(ws+OFF_CS+2*HSS+tid), rCS3=ldA(ws+OFF_CS+3*HSS+tid),
                rCBS=ldA(ws+OFF_CBS+tid);
    const float rCR0=ldA(ws+OFF_CR+tid), rCR1=ldA(ws+OFF_CR+HSS+tid),
                rCR2=ldA(ws+OFF_CR+2*HSS+tid), rCR3=ldA(ws+OFF_CR+3*HSS+tid),
                rCBR=ldA(ws+OFF_CBR+tid), rCSR=ldA(ws+OFF_CSR+tid);
    float rCP0=0,rCP1=0,rCP2=0,rCP3=0,rCBP=0;
    if (tid < HPP) {
      rCP0=ldA(ws+OFF_CP+tid); rCP1=ldA(ws+OFF_CP+HPP+tid);
      rCP2=ldA(ws+OFF_CP+2*HPP+tid); rCP3=ldA(ws+OFF_CP+3*HPP+tid);
      rCBP=ldA(ws+OFF_CBP+tid);
    }

    for (int t = 0; t < BSZ; ++t) {
      if (tid < NOWN) { while (ldAu(&bar[tid]) < (unsigned)(t+1)) __builtin_amdgcn_s_sleep(1); }
      __syncthreads();
      // ======== chain(t) ========
      const float* st = p.state + (size_t)t*4;
      const float s0 = st[0], s1 = st[1], s2 = st[2], s3 = st[3];
      if (tid < EE)
        sSE[tid] = s0*p.Wemb[tid] + s1*p.Wemb[EE+tid]
                 + s2*p.Wemb[2*EE+tid] + s3*p.Wemb[3*EE+tid] + p.bemb[tid];
      float er0 = expf(ldA(ws + OFF_R0 + t));
      float v = (tid < NOWN) ? ldA(ws + OFF_ES + (size_t)(t&1)*NOWN + tid) : 0.f;
      float invd = 1.f / (er0 + brs(v, s8, tid));
      {
        const int e4 = (tid & 31) * 4, qg = tid >> 5;
        f4 vv[4];
        ldA4x4(ws + OFF_EV + (size_t)(t&1)*NOWN*EE + (size_t)(qg*4)*EE + e4, EE, vv);
        f4 acc = vv[0]+vv[1]+vv[2]+vv[3];
        *(f4*)(sBuf + (size_t)qg*EE + e4) = acc;
      }
      __syncthreads();
      if (tid < EE) {
        float s = 0.f;
        #pragma unroll
        for (int q = 0; q < 16; ++q) s += sBuf[(size_t)q*EE + tid];
        sMS[tid] = (er0*sSE[tid] + s) * invd;
      }
      __syncthreads();
      { // trunk h (mem half of Ws)
        f4 a = {0.f,0.f,0.f,0.f};
        const float* base = p.Ws + (size_t)(EE + eg4*32)*HSS + hq;
        for (int i = 0; i < 32; ++i)
          a += sMS[eg4*32 + i] * (*(const f4*)(base + (size_t)i*HSS));
        *(f4*)(sBuf + (size_t)eg4*HSS + hq) = a;
      }
      __syncthreads();
      float hv;
      {
        float sh0 = s0*rCS0 + s1*rCS1 + s2*rCS2 + s3*rCS3 + rCBS;
        hv = fmaxf(sBuf[tid] + sBuf[HSS+tid] + sBuf[2*HSS+tid] + sBuf[3*HSS+tid]
                   + sh0 + p.bs[tid], 0.f);
      }
      __syncthreads();
      {
        float pa[6];
        #pragma unroll
        for (int aa = 0; aa < 5; ++aa) pa[aa] = hv * p.Wa[(size_t)tid*5 + aa];
        pa[5] = hv * p.Wc[tid];
        brsN<6>(pa, sR48, tid);
        if (tid == 0) {
          float l0=pa[0]+p.ba[0], l1=pa[1]+p.ba[1], l2=pa[2]+p.ba[2];
          float l3=pa[3]+p.ba[3], l4=pa[4]+p.ba[4];
          float mx = fmaxf(fmaxf(fmaxf(l0,l1),fmaxf(l2,l3)), l4);
          float e0=expf(l0-mx),e1=expf(l1-mx),e2=expf(l2-mx),e3=expf(l3-mx),e4v=expf(l4-mx);
          float is = 1.f/(e0+e1+e2+e3+e4v);
          float p0=e0*is,p1=e1*is,p2=e2*is,p3=e3*is,p4=e4v*is;
          if (g == 0) {
            p.out[(size_t)t*5+0]=p0; p.out[(size_t)t*5+1]=p1; p.out[(size_t)t*5+2]=p2;
            p.out[(size_t)t*5+3]=p3; p.out[(size_t)t*5+4]=p4;
            p.out[(size_t)BSZ*5 + t] = pa[5] + p.bc[0];
          }
          sSm[1]=p0; sSm[2]=p1; sSm[3]=p2; sSm[4]=p3; sSm[5]=p4; sSm[6]=pa[5]+p.bc[0];
        }
        __syncthreads();
      }
      { // p1 stream (mem half of Wp1)
        const int cq = (tid & 63) * 4, eg8 = tid >> 6;
        f4 a = {0.f,0.f,0.f,0.f};
        const float* base = p.Wp1 + (size_t)(EE + eg8*16)*HPP + cq;
        for (int i = 0; i < 16; ++i)
          a += sMS[eg8*16 + i] * (*(const f4*)(base + (size_t)i*HPP));
        *(f4*)(sBuf + (size_t)eg8*HPP + cq) = a;
      }
      __syncthreads();
      if (tid < HPP) {
        float acc = s0*rCP0 + s1*rCP1 + s2*rCP2 + s3*rCP3 + rCBP + p.bp1[tid];
        #pragma unroll
        for (int q = 0; q < 8; ++q) acc += sBuf[(size_t)q*HPP + tid];
        #pragma unroll
        for (int aa = 0; aa < 5; ++aa) acc += sSm[1+aa] * p.Wp1[(size_t)(2*EE+aa)*HPP + tid];
        acc += sSm[6] * p.Wp1[(size_t)(2*EE+5)*HPP + tid];
        sP1[tid] = fmaxf(acc, 0.f);
      }
      __syncthreads();
      { // ms2 stream
        const int cq = (tid & 31) * 4, kg = tid >> 5;
        f4 a = {0.f,0.f,0.f,0.f};
        const float* base = p.Wp2 + (size_t)(kg*16)*EE + cq;
        for (int i = 0; i < 16; ++i)
          a += sP1[kg*16 + i] * (*(const f4*)(base + (size_t)i*EE));
        *(f4*)(sBuf + (size_t)kg*EE + cq) = a;
      }
      __syncthreads();
      if (tid < EE) {
        float s = 0.f;
        #pragma unroll
        for (int q = 0; q < 16; ++q) s += sBuf[(size_t)q*EE + tid];
        sMS2[tid] = s + p.bp2[tid];
      }
      __syncthreads();
      if (t == BSZ-1) break;
      // ======== slices ========
      {
        const int h8 = tid >> 6, ee = tid & 63;
        const int h = 8*g + h8;
        float m1 = sMS2[ee], m2 = sMS2[ee+64];
        float pr = m1*p.Wr1[(size_t)ee*HSS+h] + m2*p.Wr1[(size_t)(ee+64)*HSS+h];
        float pw = m1*p.Ww1[(size_t)ee*HSS+h] + m2*p.Ww1[(size_t)(ee+64)*HSS+h];
        for (int o = 32; o > 0; o >>= 1) {
          pr += __shfl_down(pr, o, 64);
          pw += __shfl_down(pw, o, 64);
        }
        if (ee == 0) {
          stA(ws + OFF_MSR + (size_t)(t&1)*HSS + h, pr);
          stA(ws + OFF_MSW + (size_t)(t&1)*HSS + h, pw);
        }
      }
      drainSync();
      if (tid == 0) stAu(&bar[64+g], (unsigned)(t+1));
      if (tid == 0) {
        f4 w0 = ldA4(ws + OFF_W0 + (size_t)t*MM + c0);
        sSm[8+0]=expf(w0.x); sSm[8+1]=expf(w0.y); sSm[8+2]=expf(w0.z); sSm[8+3]=expf(w0.w);
      }
      // ======== slice exchange ========
      if (tid < NOWN) { while (ldAu(&bar[64+tid]) < (unsigned)(t+1)) __builtin_amdgcn_s_sleep(1); }
      __syncthreads();
      sMSR[tid]  = ldA(ws + OFF_MSR + (size_t)(t&1)*HSS + tid);
      sMSWv[tid] = ldA(ws + OFF_MSW + (size_t)(t&1)*HSS + tid);
      __syncthreads();
      // hm + sw1
      float swv[ROWS];
      {
        float hm = fmaxf(sMSWv[tid] + rBw1v, 0.f);
        swv[0]=hm*wcol.x; swv[1]=hm*wcol.y; swv[2]=hm*wcol.z; swv[3]=hm*wcol.w;
        brsN<ROWS>(swv, sR48, tid);
      }
      // ======== bulk in ========
      if (tid == 0) { while (ldAu(&bar[256+g]) < (unsigned)(t+1)) __builtin_amdgcn_s_sleep(1); }
      __syncthreads();
      if (tid == 0) {
        f4 d = ldA4(ws + OFF_BD + g*ROWS);
        sD[0]=d.x; sD[1]=d.y; sD[2]=d.z; sD[3]=d.w;
      }
      {
        const int e = tid & 127, r = tid >> 7;
        sP[r][e] = ldA(ws + OFF_BP + ((size_t)g*ROWS + r)*EE + e);
      }
      #pragma unroll
      for (int r = 0; r < ROWS; ++r)
        sPW[r][tid] = ldA(ws + OFF_PWRD + ((size_t)g*ROWS + r)*HSS + tid);
      __syncthreads();
      // ======== dFinish ========
      {
        const int e = tid & 127, r = tid >> 7;
        float ew1 = expf(swv[r] + p.bw2[c0+r]);
        float ew0 = sSm[8+r];
        float inv = 1.f / (sD[r] + ew0 + ew1);
        float x = (sP[r][e] + ew0*sSE[e] + ew1*sMS2[e]) * inv;
        float mn = x, mx = x;
        #pragma unroll
        for (int o = 1; o < 64; o <<= 1) {
          mn = fminf(mn, __shfl_xor(mn, o, 64));
          mx = fmaxf(mx, __shfl_xor(mx, o, 64));
        }
        if ((tid & 63) == 0) { sRed[(tid>>6)*2] = mn; sRed[(tid>>6)*2+1] = mx; }
        __syncthreads();
        mn = fminf(sRed[4*r], sRed[4*r+2]);
        mx = fmaxf(sRed[4*r+1], sRed[4*r+3]);
        float k = 1.f / (mx - mn);
        float xr = (x - mn) * k + sPE[r][e];
        stA(ws + OFF_MP + (size_t)((t+1)&1)*MM*EE + (size_t)(c0+r)*EE + e, xr);
        sX[r][e] = xr;
        if (tid < 4) {
          int rr = tid;
          float ew1b = expf(swv[rr] + p.bw2[c0+rr]);
          float invb = 1.f / (sD[rr] + sSm[8+rr] + ew1b);
          float mnb = fminf(sRed[4*rr], sRed[4*rr+2]);
          float mxb = fmaxf(sRed[4*rr+1], sRed[4*rr+3]);
          float kb = 1.f / (mxb - mnb);
          float a = kb * invb;
          float b = a * sSm[8+rr];
          float c = a * ew1b;
          float d = -mnb * kb;
          stA(ws + OFF_SCAL + (size_t)(c0+rr)*4 + 0, a);
          stA(ws + OFF_SCAL + (size_t)(c0+rr)*4 + 1, b);
          stA(ws + OFF_SCAL + (size_t)(c0+rr)*4 + 2, c);
          stA(ws + OFF_SCAL + (size_t)(c0+rr)*4 + 3, d);
          sSm[16+rr*4+0]=a; sSm[16+rr*4+1]=b; sSm[16+rr*4+2]=c; sSm[16+rr*4+3]=d;
        }
      }
      drainSync();
      if (tid == 0) stAu(&bar[128+g], (unsigned)(t+2));   // rows(t+1)+scalars
      // ======== stageA-linear(t+1) ========
      {
        float seW = s0*rCR0 + s1*rCR1 + s2*rCR2 + s3*rCR3 + rCBR;
        float sc[ROWS];
        #pragma unroll
        for (int r = 0; r < ROWS; ++r) {
          float pre = sSm[16+r*4+0]*sPW[r][tid] + sSm[16+r*4+1]*seW
                    + sSm[16+r*4+2]*sMSR[tid] + sSm[16+r*4+3]*rCSR
                    + rPWRpe[r] + rBr1;
          sc[r] = fmaxf(pre, 0.f) * rWr2;
        }
        brsN<ROWS>(sc, sR48, tid);
        float es[ROWS];
        #pragma unroll
        for (int r = 0; r < ROWS; ++r) es[r] = expf(sc[r] + p.br2[0]);
        if (tid < EE) {
          float vv = es[0]*sX[0][tid] + es[1]*sX[1][tid] + es[2]*sX[2][tid] + es[3]*sX[3][tid];
          stA(ws + OFF_EV + (size_t)((t+1)&1)*NOWN*EE + (size_t)g*EE + tid, vv);
        }
        if (tid == 0) stA(ws + OFF_ES + (size_t)((t+1)&1)*NOWN + g, es[0]+es[1]+es[2]+es[3]);
      }
      drainSync();
      if (tid == 0) stAu(&bar[g], (unsigned)(t+2));
    }
  } else {
    // -------- HELPER prologue --------
    const float rBw1 = p.bw1[tid];
    if (tid == 0) { while (ldAu(&bar[128+og]) < 1u) __builtin_amdgcn_s_sleep(1); }
    __syncthreads();
    {
      const int e = tid & 127, r = tid >> 7;
      sPE[r][e] = ldA(ws + OFF_PE + (size_t)(c0+r)*EE + e);
      sX[r][e]  = ldA(ws + OFF_MP + (size_t)(c0+r)*EE + e);
    }
    __syncthreads();
    streamPW(p.Ww1, sPE);
    float rPWWpe[ROWS];
    #pragma unroll
    for (int r = 0; r < ROWS; ++r) {
      ws[OFF_PWWpe + (size_t)(c0+r)*HSS + tid] = sPW[r][tid];
      rPWWpe[r] = sPW[r][tid];
    }
    __syncthreads();
    { // stageC_full(0)
      {
        f4 a0={0.f,0.f,0.f,0.f},a1=a0,a2=a0,a3=a0;
        const float* base = p.Ww1 + (size_t)(eg4*32)*HSS + hq;
        for (int i = 0; i < 32; ++i) {
          f4 w = *(const f4*)(base + (size_t)i*HSS);
          int e = eg4*32 + i;
          a0 += sX[0][e]*w; a1 += sX[1][e]*w; a2 += sX[2][e]*w; a3 += sX[3][e]*w;
        }
        *(f4*)(sBuf + ((size_t)eg4*ROWS + 0)*HSS + hq) = a0;
        *(f4*)(sBuf + ((size_t)eg4*ROWS + 1)*HSS + hq) = a1;
        *(f4*)(sBuf + ((size_t)eg4*ROWS + 2)*HSS + hq) = a2;
        *(f4*)(sBuf + ((size_t)eg4*ROWS + 3)*HSS + hq) = a3;
      }
      __syncthreads();
      #pragma unroll
      for (int r = 0; r < ROWS; ++r)
        sH4[r][tid] = fmaxf(sBuf[(0*ROWS+r)*HSS+tid] + sBuf[(1*ROWS+r)*HSS+tid]
                          + sBuf[(2*ROWS+r)*HSS+tid] + sBuf[(3*ROWS+r)*HSS+tid] + rBw1, 0.f);
      __syncthreads();
      ww2pass(ws + OFF_SW);
    }
    drainSync();
    if (tid == 0) stAu(&bar[192+og], 1u);
    if (tid < 64) { while (ldAu(&bar[192+tid]) < 1u) __builtin_amdgcn_s_sleep(1); }
    else if (tid < 128) { while (ldAu(&bar[128+tid-64]) < 1u) __builtin_amdgcn_s_sleep(1); }
    __syncthreads();
    // preload composed regs (owner0 P0a complete since all rowFlags >= 1)
    const float rCW0=ldA(ws+OFF_CW2+tid), rCW1=ldA(ws+OFF_CW2+HSS+tid),
                rCW2v=ldA(ws+OFF_CW2+2*HSS+tid), rCW3=ldA(ws+OFF_CW2+3*HSS+tid),
                rCBW=ldA(ws+OFF_CBW+tid), rCSW=ldA(ws+OFF_CSW+tid);
    dBulkH(0);
    streamPW(p.Wr1, sP);
    #pragma unroll
    for (int r = 0; r < ROWS; ++r)
      stA(ws + OFF_PWRD + ((size_t)og*ROWS + r)*HSS + tid, sPW[r][tid]);
    drainSync();
    if (tid == 0) stAu(&bar[256+og], 1u);
    streamPW(p.Ww1, sP);   // local PWw(0)

    for (int t = 0; t < BSZ-2; ++t) {
      // 1. MSW slices(t)
      if (tid < 64) { while (ldAu(&bar[64+tid]) < (unsigned)(t+1)) __builtin_amdgcn_s_sleep(1); }
      __syncthreads();
      sMSWv[tid] = ldA(ws + OFF_MSW + (size_t)(t&1)*HSS + tid);
      // 2. scalars rows(t+1)
      if (tid == 0) { while (ldAu(&bar[128+og]) < (unsigned)(t+2)) __builtin_amdgcn_s_sleep(1); }
      __syncthreads();
      if (tid < 16) sSm[16+tid] = ldA(ws + OFF_SCAL + (size_t)c0*4 + tid);
      __syncthreads();
      // 3. stageC-linear(t+1)
      {
        const float* st = p.state + (size_t)t*4;
        float seW = st[0]*rCW0 + st[1]*rCW1 + st[2]*rCW2v + st[3]*rCW3 + rCBW;
        #pragma unroll
        for (int r = 0; r < ROWS; ++r) {
          float pre = sSm[16+r*4+0]*sPW[r][tid] + sSm[16+r*4+1]*seW
                    + sSm[16+r*4+2]*sMSWv[tid] + sSm[16+r*4+3]*rCSW
                    + rPWWpe[r] + rBw1;
          sH4[r][tid] = fmaxf(pre, 0.f);
        }
      }
      __syncthreads();
      // 4. scores(t+1)
      ww2pass(ws + OFF_SW + (size_t)((t+1)&1)*MM*MM);
      drainSync();
      if (tid == 0) stAu(&bar[192+og], (unsigned)(t+2));
      // 5. all scores + rows for t+1
      if (tid < 64) { while (ldAu(&bar[192+tid]) < (unsigned)(t+2)) __builtin_amdgcn_s_sleep(1); }
      else if (tid < 128) { while (ldAu(&bar[128+tid-64]) < (unsigned)(t+2)) __builtin_amdgcn_s_sleep(1); }
      __syncthreads();
      // 6. dBulk(t+1)
      dBulkH(t+1);
      // 7. publish PWr(t+1), then local PWw(t+1)
      streamPW(p.Wr1, sP);
      #pragma unroll
      for (int r = 0; r < ROWS; ++r)
        stA(ws + OFF_PWRD + ((size_t)og*ROWS + r)*HSS + tid, sPW[r][tid]);
      drainSync();
      if (tid == 0) stAu(&bar[256+og], (unsigned)(t+2));
      streamPW(p.Ww1, sP);
    }
  }
}

extern "C" void kernel_launch(void* const* d_in, const int* in_sizes, int n_in,
                              void* d_out, int out_size, void* d_ws, size_t ws_size,
                              hipStream_t stream) {
  hipMemsetAsync(d_ws, 0, 2048, stream);
  KParams kp;
  kp.state = (const float*)d_in[0];
  kp.mem0  = (const float*)d_in[1];
  kp.Wemb  = (const float*)d_in[2];
  kp.bemb  = (const float*)d_in[3];
  kp.Wr1   = (const float*)d_in[4];
  kp.br1   = (const float*)d_in[5];
  kp.Wr2   = (const float*)d_in[6];
  kp.br2   = (const float*)d_in[7];
  kp.Ww1   = (const float*)d_in[8];
  kp.bw1   = (const float*)d_in[9];
  kp.Ww2   = (const float*)d_in[10];
  kp.bw2   = (const float*)d_in[11];
  kp.Ws    = (const float*)d_in[12];
  kp.bs    = (const float*)d_in[13];
  kp.Wa    = (const float*)d_in[14];
  kp.ba    = (const float*)d_in[15];
  kp.Wc    = (const float*)d_in[16];
  kp.bc    = (const float*)d_in[17];
  kp.Wp1   = (const float*)d_in[18];
  kp.bp1   = (const float*)d_in[19];
  kp.Wp2   = (const float*)d_in[20];
  kp.bp2   = (const float*)d_in[21];
  kp.out   = (float*)d_out;
  kp.ws    = (float*)d_ws;
  toyac_kernel<<<dim3(NBLK), dim3(TPB), 0, stream>>>(kp);
}

// Round 10
// 50270.996 us; speedup vs baseline: 1.2249x; 1.2249x over previous
//
#include <hip/hip_runtime.h>
#include <math.h>

#define BSZ 2048
#define MM  256
#define EE  128
#define HSS 512
#define HPP 256
#define NOWN 64
#define NBLK 129
#define LEADER 128
#define TPB 512
#define ROWS 4

typedef float f4 __attribute__((ext_vector_type(4)));

// ---- padded flag layout (1 flag per 128B line) ----
// uint view: MSQ at [0]; ROWQ(g)=(1+g)*32; SCQ(g)=(65+g)*32   (ends at 4128 uints)
#define MSQ_IDX   0
#define ROWQ(g)   ((1+(g))*32)
#define SCQ(g)    ((65+(g))*32)
// float offsets:
#define OFF_ES    4160                  // [2][64] lines: +(par*64+g)*32  (value-as-flag, >0)
#define OFF_BD    8256                  // [64] lines: +g*32, 4 floats    (value-as-flag, >0)
#define OFF_PE    10304
#define OFF_R0    (OFF_PE + MM*EE)
#define OFF_W0    (OFF_R0 + BSZ)
#define OFF_MP    (OFF_W0 + BSZ*MM)     // [2][MM][EE]
#define OFF_SW    (OFF_MP + 2*MM*EE)    // [2][MM][MM]
#define OFF_EV    (OFF_SW + 2*MM*MM)    // [NOWN][EE] (single buffer, gated)
#define OFF_CS    (OFF_EV + NOWN*EE)    // Wemb@Ws[0:128]: 4*HSS (leader-local)
#define OFF_CBS   (OFF_CS + 4*HSS)
#define OFF_CP    (OFF_CBS + HSS)       // Wemb@Wp1[0:128]: 4*HPP
#define OFF_CBP   (OFF_CP + 4*HPP)
#define OFF_MS2   (OFF_CBP + HPP)       // EE
#define OFF_BP    (OFF_MS2 + EE)        // NOWN*ROWS*EE
// memset bytes = OFF_PE*4 = 41216

struct KParams {
  const float *state, *mem0, *Wemb, *bemb, *Wr1, *br1, *Wr2, *br2;
  const float *Ww1, *bw1, *Ww2, *bw2, *Ws, *bs, *Wa, *ba, *Wc, *bc;
  const float *Wp1, *bp1, *Wp2, *bp2;
  float *out;
  float *ws;
};

__device__ __forceinline__ float ldA(const float* p) {
  return __hip_atomic_load(p, __ATOMIC_RELAXED, __HIP_MEMORY_SCOPE_AGENT);
}
__device__ __forceinline__ void stA(float* p, float v) {
  __hip_atomic_store(p, v, __ATOMIC_RELAXED, __HIP_MEMORY_SCOPE_AGENT);
}
__device__ __forceinline__ unsigned ldAu(const unsigned* p) {
  return __hip_atomic_load(p, __ATOMIC_RELAXED, __HIP_MEMORY_SCOPE_AGENT);
}
__device__ __forceinline__ void stAu(unsigned* p, unsigned v) {
  __hip_atomic_store(p, v, __ATOMIC_RELAXED, __HIP_MEMORY_SCOPE_AGENT);
}

__device__ __forceinline__ void ldA4x8(const float* p, int strideF, f4* v) {
  const float *p1=p+strideF, *p2=p+2*strideF, *p3=p+3*strideF,
              *p4=p+4*strideF, *p5=p+5*strideF, *p6=p+6*strideF, *p7=p+7*strideF;
  asm volatile(
    "global_load_dwordx4 %0, %8, off sc0 sc1\n\t"
    "global_load_dwordx4 %1, %9, off sc0 sc1\n\t"
    "global_load_dwordx4 %2, %10, off sc0 sc1\n\t"
    "global_load_dwordx4 %3, %11, off sc0 sc1\n\t"
    "global_load_dwordx4 %4, %12, off sc0 sc1\n\t"
    "global_load_dwordx4 %5, %13, off sc0 sc1\n\t"
    "global_load_dwordx4 %6, %14, off sc0 sc1\n\t"
    "global_load_dwordx4 %7, %15, off sc0 sc1\n\t"
    "s_waitcnt vmcnt(0)"
    : "=&v"(v[0]), "=&v"(v[1]), "=&v"(v[2]), "=&v"(v[3]),
      "=&v"(v[4]), "=&v"(v[5]), "=&v"(v[6]), "=&v"(v[7])
    : "v"(p), "v"(p1), "v"(p2), "v"(p3), "v"(p4), "v"(p5), "v"(p6), "v"(p7)
    : "memory");
}
__device__ __forceinline__ void ldA4x4(const float* p, int strideF, f4* v) {
  const float *p1=p+strideF, *p2=p+2*strideF, *p3=p+3*strideF;
  asm volatile(
    "global_load_dwordx4 %0, %4, off sc0 sc1\n\t"
    "global_load_dwordx4 %1, %5, off sc0 sc1\n\t"
    "global_load_dwordx4 %2, %6, off sc0 sc1\n\t"
    "global_load_dwordx4 %3, %7, off sc0 sc1\n\t"
    "s_waitcnt vmcnt(0)"
    : "=&v"(v[0]), "=&v"(v[1]), "=&v"(v[2]), "=&v"(v[3])
    : "v"(p), "v"(p1), "v"(p2), "v"(p3)
    : "memory");
}
__device__ __forceinline__ f4 ldA4(const float* p) {
  f4 r;
  asm volatile("global_load_dwordx4 %0, %1, off sc0 sc1\n\ts_waitcnt vmcnt(0)"
    : "=&v"(r) : "v"(p) : "memory");
  return r;
}

__device__ __forceinline__ void drainSync() {
  asm volatile("s_waitcnt vmcnt(0)" ::: "memory");
  __syncthreads();
}

__device__ __forceinline__ float brs(float v, float* s8, int tid) {
  for (int o = 32; o > 0; o >>= 1) v += __shfl_down(v, o, 64);
  __syncthreads();
  if ((tid & 63) == 0) s8[tid >> 6] = v;
  __syncthreads();
  float r = s8[0]+s8[1]+s8[2]+s8[3]+s8[4]+s8[5]+s8[6]+s8[7];
  __syncthreads();
  return r;
}

template<int N>
__device__ __forceinline__ void brsN(float* v, float* sred, int tid) {
  #pragma unroll
  for (int k = 0; k < N; ++k)
    for (int o = 32; o > 0; o >>= 1) v[k] += __shfl_down(v[k], o, 64);
  __syncthreads();
  if ((tid & 63) == 0) {
    const int w = tid >> 6;
    #pragma unroll
    for (int k = 0; k < N; ++k) sred[k*8 + w] = v[k];
  }
  __syncthreads();
  #pragma unroll
  for (int k = 0; k < N; ++k) {
    float s = sred[k*8 + 0];
    #pragma unroll
    for (int w = 1; w < 8; ++w) s += sred[k*8 + w];
    v[k] = s;
  }
  __syncthreads();
}

__global__ __launch_bounds__(TPB)
void toyac_kernel(KParams p) {
  const int g = blockIdx.x;
  const int tid = threadIdx.x;
  float* ws = p.ws;
  unsigned* bar = (unsigned*)p.ws;
  const int isOwner = (g < NOWN);
  const int og = (g >= NOWN && g < LEADER) ? (g - NOWN) : g;
  const int c0 = ROWS * ((g < NOWN) ? g : og);

  __shared__ float sBuf[8192];
  __shared__ float sH4[ROWS][HSS];   // helper hidden; alias sEv in dBulk
  __shared__ float sX[ROWS][EE];
  __shared__ float sP[ROWS][EE];
  __shared__ float sPE[ROWS][EE];
  __shared__ float sHv[HSS];         // P0b + leader trunk
  __shared__ float sMS[EE];
  __shared__ float sMS2[EE];
  __shared__ float sSE[EE];
  __shared__ float sP1[HPP];
  __shared__ float sD[ROWS];
  __shared__ float sR48[48];
  __shared__ float s8[8];
  __shared__ float sRed[16];
  __shared__ float sSm[40];

  float (*sEv)[MM] = (float(*)[MM])sH4;

  const int hq = (tid & 127) * 4;
  const int eg4 = tid >> 7;

  // ================= P0a =================
  if (isOwner) {
    const int e = tid & 127, r = tid >> 7, c = c0 + r;
    double dv = exp(-(double)(2*(e>>1)) * log(10000.0) / 128.0);
    double arg = (double)c * dv;
    float pev = ((e & 1) == 0) ? (float)sin(arg) : (float)cos(arg);
    sPE[r][e] = pev;
    float m0v = p.mem0[(size_t)c*EE + e] + pev;
    stA(ws + OFF_MP + (size_t)c*EE + e, m0v);
    sX[r][e] = m0v;
  } else if (g == LEADER) {
    for (int jj = tid; jj < HSS; jj += TPB) {
      float a0=0.f,a1=0.f,a2=0.f,a3=0.f,cb=0.f;
      for (int e = 0; e < EE; ++e) {
        float wv = p.Ws[(size_t)e*HSS + jj];
        a0 += p.Wemb[e]*wv; a1 += p.Wemb[EE+e]*wv;
        a2 += p.Wemb[2*EE+e]*wv; a3 += p.Wemb[3*EE+e]*wv;
        cb += p.bemb[e]*wv;
      }
      ws[OFF_CS + jj] = a0; ws[OFF_CS + HSS + jj] = a1;
      ws[OFF_CS + 2*HSS + jj] = a2; ws[OFF_CS + 3*HSS + jj] = a3;
      ws[OFF_CBS + jj] = cb;
    }
    if (tid < HPP) {
      int k = tid;
      float a0=0.f,a1=0.f,a2=0.f,a3=0.f,cb=0.f;
      for (int e = 0; e < EE; ++e) {
        float wv = p.Wp1[(size_t)e*HPP + k];
        a0 += p.Wemb[e]*wv; a1 += p.Wemb[EE+e]*wv;
        a2 += p.Wemb[2*EE+e]*wv; a3 += p.Wemb[3*EE+e]*wv;
        cb += p.bemb[e]*wv;
      }
      ws[OFF_CP + k] = a0; ws[OFF_CP + HPP + k] = a1;
      ws[OFF_CP + 2*HPP + k] = a2; ws[OFF_CP + 3*HPP + k] = a3;
      ws[OFF_CBP + k] = cb;
    }
  }

  // ================= P0b: per-step R0, W0 (striped over 129 blocks) =================
  for (int t = g; t < BSZ; t += NBLK) {
    __syncthreads();
    if (tid < EE) {
      const float* st = p.state + (size_t)t*4;
      sSE[tid] = st[0]*p.Wemb[tid] + st[1]*p.Wemb[EE+tid]
               + st[2]*p.Wemb[2*EE+tid] + st[3]*p.Wemb[3*EE+tid] + p.bemb[tid];
    }
    __syncthreads();
    { // reader score r0
      f4 a = {0.f,0.f,0.f,0.f};
      const float* base = p.Wr1 + (size_t)(eg4*32)*HSS + hq;
      for (int i = 0; i < 32; ++i)
        a += sSE[eg4*32 + i] * (*(const f4*)(base + (size_t)i*HSS));
      *(f4*)(sBuf + (size_t)eg4*HSS + hq) = a;
      __syncthreads();
      int h = tid;
      float hid = sBuf[h] + sBuf[HSS+h] + sBuf[2*HSS+h] + sBuf[3*HSS+h] + p.br1[h];
      float v = fmaxf(hid, 0.f) * p.Wr2[h];
      float sc = brs(v, s8, tid);
      if (tid == 0) stA(ws + OFF_R0 + t, sc + p.br2[0]);
      __syncthreads();
    }
    { // writer row0
      f4 a = {0.f,0.f,0.f,0.f};
      const float* base = p.Ww1 + (size_t)(eg4*32)*HSS + hq;
      for (int i = 0; i < 32; ++i)
        a += sSE[eg4*32 + i] * (*(const f4*)(base + (size_t)i*HSS));
      *(f4*)(sBuf + (size_t)eg4*HSS + hq) = a;
      __syncthreads();
      int h = tid;
      sHv[h] = fmaxf(sBuf[h] + sBuf[HSS+h] + sBuf[2*HSS+h] + sBuf[3*HSS+h] + p.bw1[h], 0.f);
      __syncthreads();
      const int cq = (tid & 63) * 4, hg = tid >> 6;
      f4 q = {0.f,0.f,0.f,0.f};
      const float* b2 = p.Ww2 + (size_t)(hg*64)*MM + cq;
      for (int i = 0; i < 64; ++i)
        q += sHv[hg*64 + i] * (*(const f4*)(b2 + (size_t)i*MM));
      *(f4*)(sBuf + (size_t)hg*MM + cq) = q;
      __syncthreads();
      if (tid < MM) {
        float s = 0.f;
        #pragma unroll
        for (int k = 0; k < 8; ++k) s += sBuf[(size_t)k*MM + tid];
        stA(ws + OFF_W0 + (size_t)t*MM + tid, s + p.bw2[tid]);
      }
      __syncthreads();
    }
  }

  // ---------- owner: stageA (full Wr1 pass); ES stored by caller after drain ----------
  auto stageA = [&](float* esSumOut) {
    {
      f4 a0={0.f,0.f,0.f,0.f},a1=a0,a2=a0,a3=a0;
      const float* base = p.Wr1 + (size_t)(eg4*32)*HSS + hq;
      for (int i = 0; i < 32; ++i) {
        f4 w = *(const f4*)(base + (size_t)i*HSS);
        int e = eg4*32 + i;
        a0 += sX[0][e]*w; a1 += sX[1][e]*w; a2 += sX[2][e]*w; a3 += sX[3][e]*w;
      }
      *(f4*)(sBuf + ((size_t)eg4*ROWS + 0)*HSS + hq) = a0;
      *(f4*)(sBuf + ((size_t)eg4*ROWS + 1)*HSS + hq) = a1;
      *(f4*)(sBuf + ((size_t)eg4*ROWS + 2)*HSS + hq) = a2;
      *(f4*)(sBuf + ((size_t)eg4*ROWS + 3)*HSS + hq) = a3;
    }
    __syncthreads();
    float sc[ROWS];
    {
      int h = tid;
      float b = p.br1[h], wr = p.Wr2[h];
      #pragma unroll
      for (int r = 0; r < ROWS; ++r) {
        float hid = sBuf[(0*ROWS+r)*HSS+h] + sBuf[(1*ROWS+r)*HSS+h]
                  + sBuf[(2*ROWS+r)*HSS+h] + sBuf[(3*ROWS+r)*HSS+h] + b;
        sc[r] = fmaxf(hid, 0.f) * wr;
      }
      brsN<ROWS>(sc, sR48, tid);
    }
    float es[ROWS];
    #pragma unroll
    for (int r = 0; r < ROWS; ++r) es[r] = expf(sc[r] + p.br2[0]);
    if (tid < EE) {
      float v = es[0]*sX[0][tid] + es[1]*sX[1][tid] + es[2]*sX[2][tid] + es[3]*sX[3][tid];
      stA(ws + OFF_EV + (size_t)g*EE + tid, v);
    }
    *esSumOut = es[0]+es[1]+es[2]+es[3];
  };

  auto ww2pass = [&](float* swdst) {
    const int cq = (tid & 63) * 4, hg = tid >> 6;
    f4 q0={0.f,0.f,0.f,0.f},q1=q0,q2=q0,q3=q0;
    const float* b2 = p.Ww2 + (size_t)(hg*64)*MM + cq;
    for (int i = 0; i < 64; ++i) {
      f4 w = *(const f4*)(b2 + (size_t)i*MM);
      int h = hg*64 + i;
      q0 += sH4[0][h]*w; q1 += sH4[1][h]*w; q2 += sH4[2][h]*w; q3 += sH4[3][h]*w;
    }
    *(f4*)(sBuf + ((size_t)hg*ROWS + 0)*MM + cq) = q0;
    *(f4*)(sBuf + ((size_t)hg*ROWS + 1)*MM + cq) = q1;
    *(f4*)(sBuf + ((size_t)hg*ROWS + 2)*MM + cq) = q2;
    *(f4*)(sBuf + ((size_t)hg*ROWS + 3)*MM + cq) = q3;
    __syncthreads();
    {
      const int col = tid & 255, rp = tid >> 8;
      #pragma unroll
      for (int rr = 0; rr < 2; ++rr) {
        int r = rp*2 + rr;
        float s = 0.f;
        #pragma unroll
        for (int k = 0; k < 8; ++k) s += sBuf[((size_t)k*ROWS + r)*MM + col];
        stA(swdst + (size_t)(c0 + r)*MM + col, s + p.bw2[col]);
      }
    }
  };

  auto stageC = [&](float* swdst) {
    {
      f4 a0={0.f,0.f,0.f,0.f},a1=a0,a2=a0,a3=a0;
      const float* base = p.Ww1 + (size_t)(eg4*32)*HSS + hq;
      for (int i = 0; i < 32; ++i) {
        f4 w = *(const f4*)(base + (size_t)i*HSS);
        int e = eg4*32 + i;
        a0 += sX[0][e]*w; a1 += sX[1][e]*w; a2 += sX[2][e]*w; a3 += sX[3][e]*w;
      }
      *(f4*)(sBuf + ((size_t)eg4*ROWS + 0)*HSS + hq) = a0;
      *(f4*)(sBuf + ((size_t)eg4*ROWS + 1)*HSS + hq) = a1;
      *(f4*)(sBuf + ((size_t)eg4*ROWS + 2)*HSS + hq) = a2;
      *(f4*)(sBuf + ((size_t)eg4*ROWS + 3)*HSS + hq) = a3;
    }
    __syncthreads();
    {
      int h = tid;
      float b = p.bw1[h];
      #pragma unroll
      for (int r = 0; r < ROWS; ++r)
        sH4[r][h] = fmaxf(sBuf[(0*ROWS+r)*HSS+h] + sBuf[(1*ROWS+r)*HSS+h]
                        + sBuf[(2*ROWS+r)*HSS+h] + sBuf[(3*ROWS+r)*HSS+h] + b, 0.f);
    }
    __syncthreads();
    ww2pass(swdst);
  };

  // helper bulk: denoms -> sD (LDS), BP stores; BD stored by caller after drain
  auto dBulkH = [&](int tt) {
    float* swc = ws + OFF_SW + (size_t)(tt&1)*MM*MM;
    float* mpc = ws + OFF_MP + (size_t)(tt&1)*MM*EE;
    float ex[ROWS] = {0.f,0.f,0.f,0.f};
    if (tid < MM) {
      f4 s = ldA4(swc + (size_t)tid*MM + c0);
      #pragma unroll
      for (int r = 0; r < ROWS; ++r) { ex[r] = expf(s[r]); sEv[r][tid] = ex[r]; }
    }
    brsN<ROWS>(ex, sR48, tid);
    if (tid == 0) { sD[0]=ex[0]; sD[1]=ex[1]; sD[2]=ex[2]; sD[3]=ex[3]; }
    {
      const int e4 = (tid & 31) * 4, rg = tid >> 5;
      f4 a0={0.f,0.f,0.f,0.f},a1=a0,a2=a0,a3=a0;
      const float* base = mpc + (size_t)(rg*16)*EE + e4;
      f4 vv[8];
      ldA4x8(base, EE, vv);
      #pragma unroll
      for (int i = 0; i < 8; ++i) {
        int r0 = rg*16 + i;
        a0 += sEv[0][r0]*vv[i]; a1 += sEv[1][r0]*vv[i];
        a2 += sEv[2][r0]*vv[i]; a3 += sEv[3][r0]*vv[i];
      }
      ldA4x8(base + 8*EE, EE, vv);
      #pragma unroll
      for (int i = 0; i < 8; ++i) {
        int r0 = rg*16 + 8 + i;
        a0 += sEv[0][r0]*vv[i]; a1 += sEv[1][r0]*vv[i];
        a2 += sEv[2][r0]*vv[i]; a3 += sEv[3][r0]*vv[i];
      }
      *(f4*)(sBuf + ((size_t)0*16 + rg)*EE + e4) = a0;
      *(f4*)(sBuf + ((size_t)1*16 + rg)*EE + e4) = a1;
      *(f4*)(sBuf + ((size_t)2*16 + rg)*EE + e4) = a2;
      *(f4*)(sBuf + ((size_t)3*16 + rg)*EE + e4) = a3;
    }
    __syncthreads();
    {
      const int e = tid & 127, r = tid >> 7;
      float s = 0.f;
      #pragma unroll
      for (int q = 0; q < 16; ++q) s += sBuf[((size_t)r*16 + q)*EE + e];
      stA(ws + OFF_BP + ((size_t)og*ROWS + r)*EE + e, s);
    }
  };

  // ================= main =================
  if (g == LEADER) {
    for (int t = 0; t < BSZ; ++t) {
      float er0 = expf(ldA(ws + OFF_R0 + t));   // pre-read before poll
      // ES poll (value-as-flag): each of 64 threads waits its owner's sum > 0
      float v = 0.f;
      if (tid < NOWN) {
        float* es = ws + OFF_ES + (size_t)((t&1)*NOWN + tid)*32;
        do { v = ldA(es); } while (v == 0.f);
        stA(es, 0.f);                            // consume + reset for t+2
      }
      float invd = 1.f / (er0 + brs(v, s8, tid));
      {
        const int e4 = (tid & 31) * 4, qg = tid >> 5;
        f4 vv[4];
        ldA4x4(ws + OFF_EV + (size_t)(qg*4)*EE + e4, EE, vv);
        f4 acc = vv[0]+vv[1]+vv[2]+vv[3];
        *(f4*)(sBuf + (size_t)qg*EE + e4) = acc;
      }
      __syncthreads();
      {
        const float* st = p.state + (size_t)t*4;
        const float s0 = st[0], s1 = st[1], s2 = st[2], s3 = st[3];
        if (tid < EE) {
          float se = s0*p.Wemb[tid] + s1*p.Wemb[EE+tid]
                   + s2*p.Wemb[2*EE+tid] + s3*p.Wemb[3*EE+tid] + p.bemb[tid];
          float s = 0.f;
          #pragma unroll
          for (int q = 0; q < 16; ++q) s += sBuf[(size_t)q*EE + tid];
          sMS[tid] = (er0*se + s) * invd;
        }
        __syncthreads();
        { // trunk hidden
          f4 a = {0.f,0.f,0.f,0.f};
          const float* base = p.Ws + (size_t)(EE + eg4*32)*HSS + hq;
          for (int i = 0; i < 32; ++i)
            a += sMS[eg4*32 + i] * (*(const f4*)(base + (size_t)i*HSS));
          *(f4*)(sBuf + (size_t)eg4*HSS + hq) = a;
        }
        __syncthreads();
        float hv;
        {
          const float* cs = ws + OFF_CS;
          float sh0 = s0*cs[tid] + s1*cs[HSS+tid] + s2*cs[2*HSS+tid] + s3*cs[3*HSS+tid]
                    + ws[OFF_CBS + tid];
          hv = fmaxf(sBuf[tid] + sBuf[HSS+tid] + sBuf[2*HSS+tid] + sBuf[3*HSS+tid]
                     + sh0 + p.bs[tid], 0.f);
        }
        __syncthreads();
        {
          float pa[6];
          #pragma unroll
          for (int aa = 0; aa < 5; ++aa) pa[aa] = hv * p.Wa[(size_t)tid*5 + aa];
          pa[5] = hv * p.Wc[tid];
          brsN<6>(pa, sR48, tid);
          if (tid == 0) {
            float l0=pa[0]+p.ba[0], l1=pa[1]+p.ba[1], l2=pa[2]+p.ba[2];
            float l3=pa[3]+p.ba[3], l4=pa[4]+p.ba[4];
            float mx = fmaxf(fmaxf(fmaxf(l0,l1),fmaxf(l2,l3)), l4);
            float e0=expf(l0-mx),e1=expf(l1-mx),e2=expf(l2-mx),e3=expf(l3-mx),e4v=expf(l4-mx);
            float is = 1.f/(e0+e1+e2+e3+e4v);
            float p0=e0*is,p1=e1*is,p2=e2*is,p3=e3*is,p4=e4v*is;
            p.out[(size_t)t*5+0]=p0; p.out[(size_t)t*5+1]=p1; p.out[(size_t)t*5+2]=p2;
            p.out[(size_t)t*5+3]=p3; p.out[(size_t)t*5+4]=p4;
            float val = pa[5] + p.bc[0];
            p.out[(size_t)BSZ*5 + t] = val;
            sSm[1]=p0; sSm[2]=p1; sSm[3]=p2; sSm[4]=p3; sSm[5]=p4; sSm[6]=val;
          }
          __syncthreads();
        }
        { // p1 stream
          const int cq = (tid & 63) * 4, eg8 = tid >> 6;
          f4 a = {0.f,0.f,0.f,0.f};
          const float* base = p.Wp1 + (size_t)(EE + eg8*16)*HPP + cq;
          for (int i = 0; i < 16; ++i)
            a += sMS[eg8*16 + i] * (*(const f4*)(base + (size_t)i*HPP));
          *(f4*)(sBuf + (size_t)eg8*HPP + cq) = a;
        }
        __syncthreads();
        if (tid < HPP) {
          const float* cp = ws + OFF_CP;
          float acc = s0*cp[tid] + s1*cp[HPP+tid] + s2*cp[2*HPP+tid] + s3*cp[3*HPP+tid]
                    + ws[OFF_CBP + tid] + p.bp1[tid];
          #pragma unroll
          for (int q = 0; q < 8; ++q) acc += sBuf[(size_t)q*HPP + tid];
          #pragma unroll
          for (int aa = 0; aa < 5; ++aa) acc += sSm[1+aa] * p.Wp1[(size_t)(2*EE+aa)*HPP + tid];
          acc += sSm[6] * p.Wp1[(size_t)(2*EE+5)*HPP + tid];
          sP1[tid] = fmaxf(acc, 0.f);
        }
        __syncthreads();
        { // ms2 stream
          const int cq = (tid & 31) * 4, kg = tid >> 5;
          f4 a = {0.f,0.f,0.f,0.f};
          const float* base = p.Wp2 + (size_t)(kg*16)*EE + cq;
          for (int i = 0; i < 16; ++i)
            a += sP1[kg*16 + i] * (*(const f4*)(base + (size_t)i*EE));
          *(f4*)(sBuf + (size_t)kg*EE + cq) = a;
        }
        __syncthreads();
        if (tid < EE) {
          float s = 0.f;
          #pragma unroll
          for (int q = 0; q < 16; ++q) s += sBuf[(size_t)q*EE + tid];
          stA(ws + OFF_MS2 + tid, s + p.bp2[tid]);
        }
      }
      drainSync();
      if (tid == 0) stAu(&bar[MSQ_IDX], (unsigned)(t+1));
    }
  } else if (isOwner) {
    // -------- OWNER --------
    const f4 wcol = *(const f4*)(p.Ww2 + (size_t)tid*MM + c0);
    const float rBw1v = p.bw1[tid];
    drainSync();
    if (tid == 0) stAu(&bar[ROWQ(g)], 1u);     // rows(0) ready
    float esSum;
    stageA(&esSum);
    drainSync();
    if (tid == 0) stA(ws + OFF_ES + (size_t)g*32, esSum);   // ES(0), parity 0, release

    for (int t = 0; t < BSZ-1; ++t) {
      // flag-independent precompute
      if (tid < EE) {
        const float* st = p.state + (size_t)t*4;
        sSE[tid] = st[0]*p.Wemb[tid] + st[1]*p.Wemb[EE+tid]
                 + st[2]*p.Wemb[2*EE+tid] + st[3]*p.Wemb[3*EE+tid] + p.bemb[tid];
      }
      if (tid == 0) {
        f4 w0 = ldA4(ws + OFF_W0 + (size_t)t*MM + c0);
        sSm[8]=expf(w0.x); sSm[9]=expf(w0.y); sSm[10]=expf(w0.z); sSm[11]=expf(w0.w);
      }
      // wait ms2(t) — busy poll
      if (tid == 0) { while (ldAu(&bar[MSQ_IDX]) < (unsigned)(t+1)) {} }
      __syncthreads();
      if (tid < EE) sMS2[tid] = ldA(ws + OFF_MS2 + tid);
      // BD poll (value-as-flag) + consume + reset
      if (tid == 0) {
        float* bd = ws + OFF_BD + (size_t)g*32;
        float x,y,z,w;
        do { x=ldA(bd); y=ldA(bd+1); z=ldA(bd+2); w=ldA(bd+3); }
        while (x==0.f || y==0.f || z==0.f || w==0.f);
        sD[0]=x; sD[1]=y; sD[2]=z; sD[3]=w;
        stA(bd,0.f); stA(bd+1,0.f); stA(bd+2,0.f); stA(bd+3,0.f);
      }
      __syncthreads();
      { // BP read (each thread its own element; consumed by same thread in dFinish)
        const int e = tid & 127, r = tid >> 7;
        sP[r][e] = ldA(ws + OFF_BP + ((size_t)g*ROWS + r)*EE + e);
      }
      // hms = relu(ms2 @ Ww1 + bw1), per-thread h = tid
      {
        f4 a = {0.f,0.f,0.f,0.f};
        const float* base = p.Ww1 + (size_t)(eg4*32)*HSS + hq;
        for (int i = 0; i < 32; ++i)
          a += sMS2[eg4*32 + i] * (*(const f4*)(base + (size_t)i*HSS));
        *(f4*)(sBuf + (size_t)eg4*HSS + hq) = a;
      }
      __syncthreads();
      float hm = fmaxf(sBuf[tid] + sBuf[HSS+tid] + sBuf[2*HSS+tid] + sBuf[3*HSS+tid]
                       + rBw1v, 0.f);
      __syncthreads();
      // sw1 for own 4 cols
      float swv[ROWS] = { hm*wcol.x, hm*wcol.y, hm*wcol.z, hm*wcol.w };
      brsN<ROWS>(swv, sR48, tid);
      // dFinish
      {
        const int e = tid & 127, r = tid >> 7;
        float ew1 = expf(swv[r] + p.bw2[c0+r]);
        float ew0 = sSm[8+r];
        float inv = 1.f / (sD[r] + ew0 + ew1);
        float x = (sP[r][e] + ew0*sSE[e] + ew1*sMS2[e]) * inv;
        float mn = x, mx = x;
        #pragma unroll
        for (int o = 1; o < 64; o <<= 1) {
          mn = fminf(mn, __shfl_xor(mn, o, 64));
          mx = fmaxf(mx, __shfl_xor(mx, o, 64));
        }
        if ((tid & 63) == 0) { sRed[(tid>>6)*2] = mn; sRed[(tid>>6)*2+1] = mx; }
        __syncthreads();
        mn = fminf(sRed[4*r], sRed[4*r+2]);
        mx = fmaxf(sRed[4*r+1], sRed[4*r+3]);
        float k = 1.f / (mx - mn);
        float xr = (x - mn) * k + sPE[r][e];
        stA(ws + OFF_MP + (size_t)((t+1)&1)*MM*EE + (size_t)(c0+r)*EE + e, xr);
        sX[r][e] = xr;
      }
      drainSync();
      if (tid == 0) stAu(&bar[ROWQ(g)], (unsigned)(t+2));  // rows(t+1)
      // stageA(t+1)
      stageA(&esSum);
      drainSync();
      if (tid == 0) stA(ws + OFF_ES + (size_t)(((t+1)&1)*NOWN + g)*32, esSum);
    }
  } else {
    // -------- HELPER --------
    for (int t = 0; t < BSZ-1; ++t) {
      if (tid == 0) {
        while (ldAu(&bar[ROWQ(og)]) < (unsigned)(t+1)) __builtin_amdgcn_s_sleep(2);
      }
      __syncthreads();
      {
        const int e = tid & 127, r = tid >> 7;
        sX[r][e] = ldA(ws + OFF_MP + (size_t)(t&1)*MM*EE + (size_t)(c0+r)*EE + e);
      }
      __syncthreads();
      stageC(ws + OFF_SW + (size_t)(t&1)*MM*MM);
      drainSync();
      if (tid == 0) stAu(&bar[SCQ(og)], (unsigned)(t+1));
      // wait all scores + all rows for step t
      if (tid < 64) {
        while (ldAu(&bar[SCQ(tid)]) < (unsigned)(t+1)) __builtin_amdgcn_s_sleep(2);
      } else if (tid < 128) {
        while (ldAu(&bar[ROWQ(tid-64)]) < (unsigned)(t+1)) __builtin_amdgcn_s_sleep(2);
      }
      __syncthreads();
      dBulkH(t);
      drainSync();        // BP visible
      if (tid == 0) {     // BD release (values > 0)
        float* bd = ws + OFF_BD + (size_t)og*32;
        stA(bd,   sD[0]); stA(bd+1, sD[1]);
        stA(bd+2, sD[2]); stA(bd+3, sD[3]);
      }
    }
  }
}

extern "C" void kernel_launch(void* const* d_in, const int* in_sizes, int n_in,
                              void* d_out, int out_size, void* d_ws, size_t ws_size,
                              hipStream_t stream) {
  hipMemsetAsync(d_ws, 0, OFF_PE * 4, stream);   // flags + ES + BD region
  KParams kp;
  kp.state = (const float*)d_in[0];
  kp.mem0  = (const float*)d_in[1];
  kp.Wemb  = (const float*)d_in[2];
  kp.bemb  = (const float*)d_in[3];
  kp.Wr1   = (const float*)d_in[4];
  kp.br1   = (const float*)d_in[5];
  kp.Wr2   = (const float*)d_in[6];
  kp.br2   = (const float*)d_in[7];
  kp.Ww1   = (const float*)d_in[8];
  kp.bw1   = (const float*)d_in[9];
  kp.Ww2   = (const float*)d_in[10];
  kp.bw2   = (const float*)d_in[11];
  kp.Ws    = (const float*)d_in[12];
  kp.bs    = (const float*)d_in[13];
  kp.Wa    = (const float*)d_in[14];
  kp.ba    = (const float*)d_in[15];
  kp.Wc    = (const float*)d_in[16];
  kp.bc    = (const float*)d_in[17];
  kp.Wp1   = (const float*)d_in[18];
  kp.bp1   = (const float*)d_in[19];
  kp.Wp2   = (const float*)d_in[20];
  kp.bp2   = (const float*)d_in[21];
  kp.out   = (float*)d_out;
  kp.ws    = (float*)d_ws;
  toyac_kernel<<<dim3(NBLK), dim3(TPB), 0, stream>>>(kp);
}